// Round 1
// 4223.843 us; speedup vs baseline: 1.0026x; 1.0026x over previous
//
#include <hip/hip_runtime.h>
#include <stdint.h>

#define TSEQ 256
#define NB   128

typedef unsigned short u16;
typedef unsigned int   u32;
typedef unsigned long long u64;
typedef __attribute__((ext_vector_type(8))) short short8;  // 8 x bf16 (4 VGPRs)
typedef __attribute__((ext_vector_type(4))) float fx4;
typedef __attribute__((ext_vector_type(4))) u32  ux4;

static __device__ __forceinline__ u16 f2bf(float f){
  u32 u = __float_as_uint(f);
  u32 r = ((u >> 16) & 1u) + 0x7fffu;   // round-to-nearest-even
  return (u16)((u + r) >> 16);
}
static __device__ __forceinline__ float sigf(float x){ return 1.0f / (1.0f + __expf(-x)); }
static __device__ __forceinline__ float tanh_(float x){
  float ax = fabsf(x);
  float e  = __expf(-2.0f * ax);
  float t  = (1.0f - e) / (1.0f + e);
  return copysignf(t, x);
}

// device-coherent (cross-XCD) 16B H-fragment load as two 8B agent-scope atomics
static __device__ __forceinline__ short8 ld_h16(const u16* p){
  u64 lo = __hip_atomic_load((u64*)p,       __ATOMIC_RELAXED, __HIP_MEMORY_SCOPE_AGENT);
  u64 hi = __hip_atomic_load((u64*)(p + 4), __ATOMIC_RELAXED, __HIP_MEMORY_SCOPE_AGENT);
  union { u64 q[2]; short8 s; } u;
  u.q[0] = lo; u.q[1] = hi;
  return u.s;
}

// ---------------- embedding gather + fp32->bf16 ----------------
__global__ __launch_bounds__(256) void k_embed(const int* __restrict__ tok,
                                               const float* __restrict__ tab,
                                               u16* __restrict__ embA){
  const int row  = blockIdx.x * 4 + (threadIdx.x >> 6);   // row = t*128 + b
  const int lane = threadIdx.x & 63;
  const int t = row >> 7;
  const int b = row & 127;
  const int tk = tok[b * TSEQ + t];
  const float* src = tab + (long)tk * 512 + lane * 8;
  const fx4 f0 = *(const fx4*)src;
  const fx4 f1 = *(const fx4*)(src + 4);
  ux4 w;
  w[0] = (u32)f2bf(f0[0]) | ((u32)f2bf(f0[1]) << 16);
  w[1] = (u32)f2bf(f0[2]) | ((u32)f2bf(f0[3]) << 16);
  w[2] = (u32)f2bf(f1[0]) | ((u32)f2bf(f1[1]) << 16);
  w[3] = (u32)f2bf(f1[2]) | ((u32)f2bf(f1[3]) << 16);
  *(ux4*)(embA + (long)row * 512 + lane * 8) = w;
}

// ---------------- tiled transpose fp32(RxC) -> bf16(CxR) ----------------
__global__ __launch_bounds__(256) void k_transpose(const float* __restrict__ in,
                                                   u16* __restrict__ out, int R, int C){
  __shared__ float tile[32][33];
  const int c0 = blockIdx.x * 32;
  const int r0 = blockIdx.y * 32;
  const int tx = threadIdx.x;   // 0..31
  const int ty = threadIdx.y;   // 0..7
#pragma unroll
  for (int i = 0; i < 4; ++i)
    tile[ty + i * 8][tx] = in[(long)(r0 + ty + i * 8) * C + c0 + tx];
  __syncthreads();
#pragma unroll
  for (int i = 0; i < 4; ++i)
    out[(long)(c0 + ty + i * 8) * R + r0 + tx] = f2bf(tile[tx][ty + i * 8]);
}

// ---------------- persistent bidirectional LSTM with fused x-projection ----------------
// 256 WGs x 256 thr, 1 WG/CU. WG = (dir, batch-half(64), 16 h -> 64 gate cols).
// Wave = (batch-32-half bh2) x (K-half kh). Wh B-frags persistent in registers.
// Dependency scope: WG (dir,bh,ch) consumes H(t-1)[b0:b0+64][:] produced ONLY by
// the 64 WGs sharing (dir,bh) -> barrier is per-group (4 independent groups), and
// it is flag-based: one uncontended agent-scope store per WG + a 64-lane parallel
// poll (1 coalesced 256B load/iter) instead of 256 serialized same-line RMWs.
__global__ __launch_bounds__(256, 1) void k_recurrent(
    const u16* __restrict__ embA,                        // (T*B, 512) bf16
    const u16* __restrict__ WxT,                         // (2*4096, 512) bf16 (f then b)
    const u16* __restrict__ WhfT, const u16* __restrict__ WhbT,   // (4096,1024) bf16
    const float* __restrict__ bhf, const float* __restrict__ bhb,
    u16* __restrict__ Hbuf,                              // [2 dir][2 buf][128][1024] bf16
    float* __restrict__ pooled,                          // [128][2048] fp32 (relu'd)
    u32* __restrict__ flags)                             // [4 grp][64 wg] step counters
{
  __shared__ float P[2][64][68];
  const int tid  = threadIdx.x;
  const int lane = tid & 63;
  const int wid  = tid >> 6;
  const int bx   = blockIdx.x;
  const int dir  = bx >> 7;
  const int bh   = (bx >> 6) & 1;
  const int grp  = bx >> 6;          // (dir,bh) group id 0..3
  const int ch   = bx & 63;
  const int h0   = ch * 16;
  const int b0   = bh * 64;
  const int bh2  = wid >> 1;
  const int kh   = wid & 1;
  const int l15  = lane & 15, l4 = lane >> 4;

  const u16*   WhT  = dir ? WhbT : WhfT;
  const float* bias = dir ? bhb : bhf;

  // persistent Wh weight fragments: this wave's 64 cols x 512-K half
  short8 Bfr[16][4];
#pragma unroll
  for (int w = 0; w < 16; ++w)
#pragma unroll
    for (int g = 0; g < 4; ++g)
      Bfr[w][g] = *(const short8*)(WhT + (long)(g * 1024 + h0 + l15) * 1024
                                       + kh * 512 + w * 32 + l4 * 8);

  // Wx row pointers (B-operand of the x-projection GEMM)
  const u16* rowBx[4];
#pragma unroll
  for (int g = 0; g < 4; ++g)
    rowBx[g] = WxT + ((long)dir * 4096 + g * 1024 + h0 + l15) * 512 + kh * 256 + l4 * 8;

  const int bl = tid >> 2;               // local batch 0..63
  const int q  = tid & 3;                // h-quad
  const int bg = b0 + bl;

  fx4 bsv[4];
#pragma unroll
  for (int g = 0; g < 4; ++g)
    bsv[g] = *(const fx4*)(bias + g * 1024 + h0 + q * 4);

  float Creg[4] = {0.f, 0.f, 0.f, 0.f};
  float pmax[4] = {-3.0e38f, -3.0e38f, -3.0e38f, -3.0e38f};

  fx4 acc[2][4];
#pragma unroll
  for (int fm = 0; fm < 2; ++fm)
#pragma unroll
    for (int g = 0; g < 4; ++g)
#pragma unroll
      for (int r = 0; r < 4; ++r) acc[fm][g][r] = 0.f;

  // x-projection for step tt accumulated into acc (no H dependency; L2-hot)
  auto prefetch_x = [&](int tt){
    const long er = (long)(dir ? (TSEQ - 1 - tt) : tt) * NB + b0 + bh2 * 32;
    const u16* rowA0 = embA + (er + l15) * 512 + kh * 256 + l4 * 8;
    const u16* rowA1 = rowA0 + 16 * 512;
#pragma unroll
    for (int w = 0; w < 8; ++w){
      short8 ax0 = *(const short8*)(rowA0 + w * 32);
      short8 ax1 = *(const short8*)(rowA1 + w * 32);
#pragma unroll
      for (int g = 0; g < 4; ++g){
        short8 bx_ = *(const short8*)(rowBx[g] + w * 32);
        acc[0][g] = __builtin_amdgcn_mfma_f32_16x16x32_bf16(ax0, bx_, acc[0][g], 0, 0, 0);
        acc[1][g] = __builtin_amdgcn_mfma_f32_16x16x32_bf16(ax1, bx_, acc[1][g], 0, 0, 0);
      }
    }
  };

  prefetch_x(0);

  for (int t = 0; t < TSEQ; ++t){
    const int rdb = (t + 1) & 1;
    const int wrb = t & 1;

    if (t > 0){
      // Wh GEMM on H(t-1): 32 rows x 64 cols over this wave's 512-K half.
      // H loads are agent-scope (bypass L1/L2 -> coherence point).
      const u16* rowH0 = Hbuf + (((long)dir * 2 + rdb) * 128 + b0 + bh2 * 32 + l15) * 1024
                              + kh * 512 + l4 * 8;
      const u16* rowH1 = rowH0 + 16 * 1024;
#pragma unroll
      for (int w = 0; w < 16; ++w){
        short8 a0 = ld_h16(rowH0 + w * 32);
        short8 a1 = ld_h16(rowH1 + w * 32);
#pragma unroll
        for (int g = 0; g < 4; ++g){
          acc[0][g] = __builtin_amdgcn_mfma_f32_16x16x32_bf16(a0, Bfr[w][g], acc[0][g], 0, 0, 0);
          acc[1][g] = __builtin_amdgcn_mfma_f32_16x16x32_bf16(a1, Bfr[w][g], acc[1][g], 0, 0, 0);
        }
      }
    }

#pragma unroll
    for (int fm = 0; fm < 2; ++fm)
#pragma unroll
      for (int g = 0; g < 4; ++g)
#pragma unroll
        for (int r = 0; r < 4; ++r)
          P[kh][bh2 * 32 + fm * 16 + l4 * 4 + r][g * 16 + l15] = acc[fm][g][r];

    __syncthreads();

    // elementwise: thread owns (1 batch x 4 h); C and running max in registers
    float gv[4][4];
#pragma unroll
    for (int g = 0; g < 4; ++g){
      const fx4 p0 = *(const fx4*)&P[0][bl][g * 16 + q * 4];
      const fx4 p1 = *(const fx4*)&P[1][bl][g * 16 + q * 4];
#pragma unroll
      for (int j = 0; j < 4; ++j) gv[g][j] = p0[j] + p1[j] + bsv[g][j];
    }

    u16 hb[4];
#pragma unroll
    for (int j = 0; j < 4; ++j){
      float i_, f_, o_;
      if (dir == 0){
        i_ = sigf(gv[0][j]); f_ = sigf(gv[1][j]); o_ = sigf(gv[2][j]);
      } else {  // reference applies sigmoid twice on backward i/f/o
        i_ = sigf(sigf(gv[0][j])); f_ = sigf(sigf(gv[1][j])); o_ = sigf(sigf(gv[2][j]));
      }
      const float cn = tanh_(gv[3][j]);
      Creg[j] = f_ * Creg[j] + i_ * cn;
      const float h = o_ * tanh_(Creg[j]);
      pmax[j] = fmaxf(pmax[j], h);
      hb[j] = f2bf(h);
    }
    {  // H(t) store: agent-scope (visible at device coherence point)
      u16* hw = Hbuf + (((long)dir * 2 + wrb) * 128 + bg) * 1024 + h0 + q * 4;
      u64 pk = (u64)hb[0] | ((u64)hb[1] << 16) | ((u64)hb[2] << 32) | ((u64)hb[3] << 48);
      __hip_atomic_store((u64*)hw, pk, __ATOMIC_RELAXED, __HIP_MEMORY_SCOPE_AGENT);
    }

    if (t + 1 < TSEQ){
      // group barrier, flag-based:
      //  arrive: drain H stores (syncthreads emits s_waitcnt vmcnt(0) before
      //  s_barrier), then ONE uncontended flag store per WG (monotone step value,
      //  no reset races). Overlap next-x prefetch, then each wave independently
      //  polls all 64 group flags with 64 lanes in parallel (1 coalesced load/iter).
      __syncthreads();
      if (tid == 0)
        __hip_atomic_store(&flags[grp * 64 + ch], (u32)(t + 1),
                           __ATOMIC_RELAXED, __HIP_MEMORY_SCOPE_AGENT);

#pragma unroll
      for (int fm = 0; fm < 2; ++fm)
#pragma unroll
        for (int g = 0; g < 4; ++g)
#pragma unroll
          for (int r = 0; r < 4; ++r) acc[fm][g][r] = 0.f;
      prefetch_x(t + 1);

      {
        const u32 target = (u32)(t + 1);
        const u32* fl = flags + grp * 64;
        for (;;){
          const u32 v = __hip_atomic_load(&fl[lane], __ATOMIC_RELAXED,
                                          __HIP_MEMORY_SCOPE_AGENT);
          if (__all(v >= target)) break;
        }
      }
      __asm__ volatile("" ::: "memory");
      // no trailing __syncthreads: every wave observed readiness itself; P-buffer
      // reads of step t completed before the drain barrier above, so next-step P
      // writes cannot race them.
    }
  }

  {  // relu(maxpool) in fp32 for the MLP head
    float* pw = pooled + (long)bg * 2048 + dir * 1024 + h0 + q * 4;
    fx4 pv;
#pragma unroll
    for (int j = 0; j < 4; ++j) pv[j] = fmaxf(pmax[j], 0.f);
    *(fx4*)pw = pv;
  }
}

// ---------------- MLP layer 1 (fp32): h = relu(pooled) @ W1 + b1 ----------------
__global__ __launch_bounds__(256) void k_mlp1(const float* __restrict__ pooled,
                                              const float* __restrict__ W1,
                                              const float* __restrict__ b1,
                                              float* __restrict__ hbuf){
  const int cb = blockIdx.x & 7, bb = blockIdx.x >> 3;
  const int c  = cb * 64 + (threadIdx.x & 63);
  const int bq = threadIdx.x >> 6;
  const int b0 = bb * 16 + bq * 4;
  float a0 = 0.f, a1 = 0.f, a2 = 0.f, a3 = 0.f;
  for (int k = 0; k < 2048; k += 4){
    const fx4 p0 = *(const fx4*)(pooled + (long)(b0 + 0) * 2048 + k);
    const fx4 p1 = *(const fx4*)(pooled + (long)(b0 + 1) * 2048 + k);
    const fx4 p2 = *(const fx4*)(pooled + (long)(b0 + 2) * 2048 + k);
    const fx4 p3 = *(const fx4*)(pooled + (long)(b0 + 3) * 2048 + k);
#pragma unroll
    for (int j = 0; j < 4; ++j){
      const float w = W1[(long)(k + j) * 512 + c];
      a0 += p0[j] * w; a1 += p1[j] * w; a2 += p2[j] * w; a3 += p3[j] * w;
    }
  }
  const float bv = b1[c];
  hbuf[(long)(b0 + 0) * 512 + c] = a0 + bv;
  hbuf[(long)(b0 + 1) * 512 + c] = a1 + bv;
  hbuf[(long)(b0 + 2) * 512 + c] = a2 + bv;
  hbuf[(long)(b0 + 3) * 512 + c] = a3 + bv;
}

// ---------------- MLP layer 2 (fp32): out = h @ W2 + b2 ----------------
__global__ __launch_bounds__(64) void k_mlp2(const float* __restrict__ hbuf,
                                             const float* __restrict__ W2,
                                             const float* __restrict__ b2,
                                             float* __restrict__ out){
  const int idx = blockIdx.x * 64 + threadIdx.x;
  if (idx >= 640) return;
  const int b = idx / 5;
  const int j = idx % 5;
  float sum = b2[j];
  for (int c = 0; c < 512; ++c)
    sum += hbuf[(long)b * 512 + c] * W2[c * 5 + j];
  out[idx] = sum;
}

extern "C" void kernel_launch(void* const* d_in, const int* in_sizes, int n_in,
                              void* d_out, int out_size, void* d_ws, size_t ws_size,
                              hipStream_t stream){
  const int*   inputs = (const int*)d_in[0];
  const float* emb_tb = (const float*)d_in[1];
  const float* Wxf = (const float*)d_in[2];
  const float* Whf = (const float*)d_in[3];
  const float* bhf = (const float*)d_in[4];
  const float* Wxb = (const float*)d_in[5];
  const float* Whb = (const float*)d_in[6];
  const float* bhb = (const float*)d_in[7];
  const float* W1  = (const float*)d_in[8];
  const float* b1  = (const float*)d_in[9];
  const float* W2  = (const float*)d_in[10];
  const float* b2  = (const float*)d_in[11];
  float* out = (float*)d_out;

  char* ws = (char*)d_ws;
  size_t off = 0;
  auto alloc = [&](size_t bytes)->char*{
    char* p = ws + off; off = (off + bytes + 511) & ~(size_t)511; return p;
  };
  u32*   flags  = (u32*)alloc(1024);                           // 4 grp x 64 wg
  u16*   embA   = (u16*)alloc((size_t)32768 * 512 * 2);        // 32 MB
  u16*   WhfT   = (u16*)alloc((size_t)4096 * 1024 * 2);        //  8 MB
  u16*   WhbT   = (u16*)alloc((size_t)4096 * 1024 * 2);        //  8 MB
  u16*   WxT    = (u16*)alloc((size_t)8192 * 512 * 2);         //  8 MB
  u16*   Hbuf   = (u16*)alloc((size_t)2 * 2 * 128 * 1024 * 2); //  1 MB
  float* pooled = (float*)alloc((size_t)128 * 2048 * 4);       //  1 MB
  float* hbuf   = (float*)alloc((size_t)128 * 512 * 4);        // .25 MB

  hipMemsetAsync(flags, 0, 1024, stream);
  k_embed<<<8192, 256, 0, stream>>>(inputs, emb_tb, embA);
  k_transpose<<<dim3(128, 32), dim3(32, 8), 0, stream>>>(Whf, WhfT, 1024, 4096);
  k_transpose<<<dim3(128, 32), dim3(32, 8), 0, stream>>>(Whb, WhbT, 1024, 4096);
  k_transpose<<<dim3(128, 16), dim3(32, 8), 0, stream>>>(Wxf, WxT, 512, 4096);
  k_transpose<<<dim3(128, 16), dim3(32, 8), 0, stream>>>(Wxb, WxT + (size_t)4096 * 512, 512, 4096);
  k_recurrent<<<256, 256, 0, stream>>>(embA, WxT, WhfT, WhbT, bhf, bhb, Hbuf, pooled, flags);
  k_mlp1<<<64, 256, 0, stream>>>(pooled, W1, b1, hbuf);
  k_mlp2<<<10, 64, 0, stream>>>(hbuf, W2, b2, out);
}

// Round 2
// 3732.905 us; speedup vs baseline: 1.1344x; 1.1315x over previous
//
#include <hip/hip_runtime.h>
#include <stdint.h>

#define TSEQ 256
#define NB   128

typedef unsigned short u16;
typedef unsigned int   u32;
typedef unsigned long long u64;
typedef __attribute__((ext_vector_type(8))) short short8;  // 8 x bf16 (4 VGPRs)
typedef __attribute__((ext_vector_type(4))) float fx4;
typedef __attribute__((ext_vector_type(4))) u32  ux4;

static __device__ __forceinline__ u16 f2bf(float f){
  u32 u = __float_as_uint(f);
  u32 r = ((u >> 16) & 1u) + 0x7fffu;   // round-to-nearest-even
  return (u16)((u + r) >> 16);
}
static __device__ __forceinline__ float sigf(float x){ return 1.0f / (1.0f + __expf(-x)); }
static __device__ __forceinline__ float tanh_(float x){
  float ax = fabsf(x);
  float e  = __expf(-2.0f * ax);
  float t  = (1.0f - e) / (1.0f + e);
  return copysignf(t, x);
}

// ---------------- embedding gather + fp32->bf16 ----------------
__global__ __launch_bounds__(256) void k_embed(const int* __restrict__ tok,
                                               const float* __restrict__ tab,
                                               u16* __restrict__ embA){
  const int row  = blockIdx.x * 4 + (threadIdx.x >> 6);   // row = t*128 + b
  const int lane = threadIdx.x & 63;
  const int t = row >> 7;
  const int b = row & 127;
  const int tk = tok[b * TSEQ + t];
  const float* src = tab + (long)tk * 512 + lane * 8;
  const fx4 f0 = *(const fx4*)src;
  const fx4 f1 = *(const fx4*)(src + 4);
  ux4 w;
  w[0] = (u32)f2bf(f0[0]) | ((u32)f2bf(f0[1]) << 16);
  w[1] = (u32)f2bf(f0[2]) | ((u32)f2bf(f0[3]) << 16);
  w[2] = (u32)f2bf(f1[0]) | ((u32)f2bf(f1[1]) << 16);
  w[3] = (u32)f2bf(f1[2]) | ((u32)f2bf(f1[3]) << 16);
  *(ux4*)(embA + (long)row * 512 + lane * 8) = w;
}

// ---------------- tiled transpose fp32(RxC) -> bf16(CxR) ----------------
__global__ __launch_bounds__(256) void k_transpose(const float* __restrict__ in,
                                                   u16* __restrict__ out, int R, int C){
  __shared__ float tile[32][33];
  const int c0 = blockIdx.x * 32;
  const int r0 = blockIdx.y * 32;
  const int tx = threadIdx.x;   // 0..31
  const int ty = threadIdx.y;   // 0..7
#pragma unroll
  for (int i = 0; i < 4; ++i)
    tile[ty + i * 8][tx] = in[(long)(r0 + ty + i * 8) * C + c0 + tx];
  __syncthreads();
#pragma unroll
  for (int i = 0; i < 4; ++i)
    out[(long)(c0 + ty + i * 8) * R + r0 + tx] = f2bf(tile[tx][ty + i * 8]);
}

// ---------------- persistent bidirectional LSTM with fused x-projection ----------------
// Re-tiled: 8 groups = (dir x batch-quarter), 32 WGs/group, WG = 32 batches x 128
// gate-cols (one gate per wave, FULL K=1024 -> no cross-wave partial sums).
// Group id = bx & 7 so a group's 32 WGs co-locate on one XCD under round-robin
// dispatch (L2-locality heuristic only; coherence stays agent-scope = correct
// under ANY placement).
// H exchange per step: WG stages its 32x1024 H tile (64 KB) with 128 contiguous
// 512B agent-scope burst loads into LDS (one MALL round trip, fully pipelined),
// then all 4 waves read MFMA fragments from LDS. vs previous: 2x less MALL
// traffic, ~12x fewer MALL line requests, loads decoupled from MFMAs.
__global__ __launch_bounds__(256, 1) void k_recurrent(
    const u16* __restrict__ embA,                        // (T*B, 512) bf16
    const u16* __restrict__ WxT,                         // (2*4096, 512) bf16 (f then b)
    const u16* __restrict__ WhfT, const u16* __restrict__ WhbT,   // (4096,1024) bf16
    const float* __restrict__ bhf, const float* __restrict__ bhb,
    u16* __restrict__ Hbuf,                              // [2 dir][2 buf][128][1024] bf16
    float* __restrict__ pooled,                          // [128][2048] fp32 (relu'd)
    u32* __restrict__ flags)                             // [8 grp][32 wg] step counters
{
  __shared__ float P[4][32][36];      // [gate][batch][32 cols + pad] (16B-aligned rows)
  __shared__ u16  Hst[32 * 1032];     // 32 rows x (1024 + 8 pad) bf16 staged H tile

  const int tid  = threadIdx.x;
  const int lane = tid & 63;
  const int ws   = tid >> 6;        // wave id == gate id (0..3)
  const int bx   = blockIdx.x;
  const int grp  = bx & 7;          // (dir, batch-quarter) group, XCD-aligned
  const int ch   = bx >> 3;         // 0..31 -> h block
  const int dir  = grp >> 2;
  const int bq   = grp & 3;
  const int h0   = ch * 32;
  const int b0   = bq * 32;
  const int l15  = lane & 15, l4 = lane >> 4;

  const u16*   WhT  = dir ? WhbT : WhfT;
  const float* bias = dir ? bhb : bhf;

  // persistent Wh B-frags: gate ws, cols h0..h0+31, full K=1024
  short8 Bfr[32][2];
#pragma unroll
  for (int w = 0; w < 32; ++w)
#pragma unroll
    for (int cf = 0; cf < 2; ++cf)
      Bfr[w][cf] = *(const short8*)(WhT + (long)(ws * 1024 + h0 + cf * 16 + l15) * 1024
                                        + w * 32 + l4 * 8);

  // Wx row pointers (B-operand of the x-projection GEMM)
  const u16* rowBx[2];
#pragma unroll
  for (int cf = 0; cf < 2; ++cf)
    rowBx[cf] = WxT + ((long)dir * 4096 + ws * 1024 + h0 + cf * 16 + l15) * 512 + l4 * 8;

  const int bl = tid >> 3;               // local batch 0..31
  const int hq = tid & 7;                // h-quad within 32-col block
  const int bg = b0 + bl;

  fx4 bsv[4];
#pragma unroll
  for (int g = 0; g < 4; ++g)
    bsv[g] = *(const fx4*)(bias + g * 1024 + h0 + hq * 4);

  float Creg[4] = {0.f, 0.f, 0.f, 0.f};
  float pmax[4] = {-3.0e38f, -3.0e38f, -3.0e38f, -3.0e38f};

  fx4 acc[2][2];
#pragma unroll
  for (int rf = 0; rf < 2; ++rf)
#pragma unroll
    for (int cf = 0; cf < 2; ++cf)
#pragma unroll
      for (int r = 0; r < 4; ++r) acc[rf][cf][r] = 0.f;

  // x-projection for step tt accumulated into acc (no H dependency; L2-hot)
  auto prefetch_x = [&](int tt){
    const long er = (long)(dir ? (TSEQ - 1 - tt) : tt) * NB + b0;
    const u16* rowA0 = embA + (er + l15) * 512 + l4 * 8;
    const u16* rowA1 = rowA0 + 16 * 512;
#pragma unroll
    for (int w = 0; w < 16; ++w){
      short8 ax0 = *(const short8*)(rowA0 + w * 32);
      short8 ax1 = *(const short8*)(rowA1 + w * 32);
      short8 bx0 = *(const short8*)(rowBx[0] + w * 32);
      short8 bx1 = *(const short8*)(rowBx[1] + w * 32);
      acc[0][0] = __builtin_amdgcn_mfma_f32_16x16x32_bf16(ax0, bx0, acc[0][0], 0, 0, 0);
      acc[0][1] = __builtin_amdgcn_mfma_f32_16x16x32_bf16(ax0, bx1, acc[0][1], 0, 0, 0);
      acc[1][0] = __builtin_amdgcn_mfma_f32_16x16x32_bf16(ax1, bx0, acc[1][0], 0, 0, 0);
      acc[1][1] = __builtin_amdgcn_mfma_f32_16x16x32_bf16(ax1, bx1, acc[1][1], 0, 0, 0);
    }
  };

  prefetch_x(0);

  char* lds = (char*)Hst;

  for (int t = 0; t < TSEQ; ++t){
    const int rdb = (t + 1) & 1;
    const int wrb = t & 1;

    if (t > 0){
      // ---- stage H(t-1) tile (32 rows x 1024 cols) into LDS, coalesced ----
      // wave ws stages rows ws*8 .. ws*8+7; per row: 4 x (64 lanes x 8B) bursts
      const u16* gsrc = Hbuf + (((long)dir * 2 + rdb) * 128 + b0) * 1024;
#pragma unroll
      for (int c = 0; c < 4; ++c){
        u64 tmp[8];
#pragma unroll
        for (int r = 0; r < 8; ++r)
          tmp[r] = __hip_atomic_load(
              (const u64*)(gsrc + (long)(ws * 8 + r) * 1024 + c * 256 + lane * 4),
              __ATOMIC_RELAXED, __HIP_MEMORY_SCOPE_AGENT);
#pragma unroll
        for (int r = 0; r < 8; ++r)
          *(u64*)(lds + (ws * 8 + r) * 2064 + c * 512 + lane * 8) = tmp[r];
      }
      __syncthreads();

      // ---- Wh GEMM from LDS: 32 rows x 32 cols (this gate) x K=1024 ----
      const char* hb0 = lds + l15 * 2064 + l4 * 16;
      const char* hb1 = hb0 + 16 * 2064;
#pragma unroll
      for (int w = 0; w < 32; ++w){
        short8 a0 = *(const short8*)(hb0 + w * 64);
        short8 a1 = *(const short8*)(hb1 + w * 64);
        acc[0][0] = __builtin_amdgcn_mfma_f32_16x16x32_bf16(a0, Bfr[w][0], acc[0][0], 0, 0, 0);
        acc[0][1] = __builtin_amdgcn_mfma_f32_16x16x32_bf16(a0, Bfr[w][1], acc[0][1], 0, 0, 0);
        acc[1][0] = __builtin_amdgcn_mfma_f32_16x16x32_bf16(a1, Bfr[w][0], acc[1][0], 0, 0, 0);
        acc[1][1] = __builtin_amdgcn_mfma_f32_16x16x32_bf16(a1, Bfr[w][1], acc[1][1], 0, 0, 0);
      }
    }

    // ---- publish this gate's 32x32 pre-activation tile ----
#pragma unroll
    for (int rf = 0; rf < 2; ++rf)
#pragma unroll
      for (int cf = 0; cf < 2; ++cf)
#pragma unroll
        for (int r = 0; r < 4; ++r)
          P[ws][rf * 16 + l4 * 4 + r][cf * 16 + l15] = acc[rf][cf][r];

    __syncthreads();

    // ---- elementwise: thread owns (1 batch x 4 h); C and max in registers ----
    float gv[4][4];
#pragma unroll
    for (int g = 0; g < 4; ++g){
      const fx4 p = *(const fx4*)&P[g][bl][hq * 4];
#pragma unroll
      for (int j = 0; j < 4; ++j) gv[g][j] = p[j] + bsv[g][j];
    }

    u16 hb16[4];
#pragma unroll
    for (int j = 0; j < 4; ++j){
      float i_, f_, o_;
      if (dir == 0){
        i_ = sigf(gv[0][j]); f_ = sigf(gv[1][j]); o_ = sigf(gv[2][j]);
      } else {  // reference applies sigmoid twice on backward i/f/o
        i_ = sigf(sigf(gv[0][j])); f_ = sigf(sigf(gv[1][j])); o_ = sigf(sigf(gv[2][j]));
      }
      const float cn = tanh_(gv[3][j]);
      Creg[j] = f_ * Creg[j] + i_ * cn;
      const float h = o_ * tanh_(Creg[j]);
      pmax[j] = fmaxf(pmax[j], h);
      hb16[j] = f2bf(h);
    }
    {  // H(t) store: agent-scope (visible at device coherence point)
      u16* hw = Hbuf + (((long)dir * 2 + wrb) * 128 + bg) * 1024 + h0 + hq * 4;
      u64 pk = (u64)hb16[0] | ((u64)hb16[1] << 16) | ((u64)hb16[2] << 32) | ((u64)hb16[3] << 48);
      __hip_atomic_store((u64*)hw, pk, __ATOMIC_RELAXED, __HIP_MEMORY_SCOPE_AGENT);
    }

    if (t + 1 < TSEQ){
      __syncthreads();   // drains every thread's H stores (vmcnt(0) before s_barrier)
      if (tid == 0)
        __hip_atomic_store(&flags[grp * 32 + ch], (u32)(t + 1),
                           __ATOMIC_RELAXED, __HIP_MEMORY_SCOPE_AGENT);

#pragma unroll
      for (int rf = 0; rf < 2; ++rf)
#pragma unroll
        for (int cf = 0; cf < 2; ++cf)
#pragma unroll
          for (int r = 0; r < 4; ++r) acc[rf][cf][r] = 0.f;
      prefetch_x(t + 1);

      if (ws == 0){   // one wave polls (32 flags, 32 lanes live), others park at barrier
        const u32 target = (u32)(t + 1);
        const u32* fl = flags + grp * 32;
        for (;;){
          const u32 v = __hip_atomic_load(&fl[lane & 31], __ATOMIC_RELAXED,
                                          __HIP_MEMORY_SCOPE_AGENT);
          if (__all(v >= target)) break;
        }
      }
      __asm__ volatile("" ::: "memory");
      __syncthreads();   // release: all group H(t) data is at the coherence point
    }
  }

  {  // relu(maxpool) in fp32 for the MLP head
    float* pw = pooled + (long)bg * 2048 + dir * 1024 + h0 + hq * 4;
    fx4 pv;
#pragma unroll
    for (int j = 0; j < 4; ++j) pv[j] = fmaxf(pmax[j], 0.f);
    *(fx4*)pw = pv;
  }
}

// ---------------- MLP layer 1 (fp32): h = relu(pooled) @ W1 + b1 ----------------
__global__ __launch_bounds__(256) void k_mlp1(const float* __restrict__ pooled,
                                              const float* __restrict__ W1,
                                              const float* __restrict__ b1,
                                              float* __restrict__ hbuf){
  const int cb = blockIdx.x & 7, bb = blockIdx.x >> 3;
  const int c  = cb * 64 + (threadIdx.x & 63);
  const int bq = threadIdx.x >> 6;
  const int b0 = bb * 16 + bq * 4;
  float a0 = 0.f, a1 = 0.f, a2 = 0.f, a3 = 0.f;
  for (int k = 0; k < 2048; k += 4){
    const fx4 p0 = *(const fx4*)(pooled + (long)(b0 + 0) * 2048 + k);
    const fx4 p1 = *(const fx4*)(pooled + (long)(b0 + 1) * 2048 + k);
    const fx4 p2 = *(const fx4*)(pooled + (long)(b0 + 2) * 2048 + k);
    const fx4 p3 = *(const fx4*)(pooled + (long)(b0 + 3) * 2048 + k);
#pragma unroll
    for (int j = 0; j < 4; ++j){
      const float w = W1[(long)(k + j) * 512 + c];
      a0 += p0[j] * w; a1 += p1[j] * w; a2 += p2[j] * w; a3 += p3[j] * w;
    }
  }
  const float bv = b1[c];
  hbuf[(long)(b0 + 0) * 512 + c] = a0 + bv;
  hbuf[(long)(b0 + 1) * 512 + c] = a1 + bv;
  hbuf[(long)(b0 + 2) * 512 + c] = a2 + bv;
  hbuf[(long)(b0 + 3) * 512 + c] = a3 + bv;
}

// ---------------- MLP layer 2 (fp32): out = h @ W2 + b2 ----------------
__global__ __launch_bounds__(64) void k_mlp2(const float* __restrict__ hbuf,
                                             const float* __restrict__ W2,
                                             const float* __restrict__ b2,
                                             float* __restrict__ out){
  const int idx = blockIdx.x * 64 + threadIdx.x;
  if (idx >= 640) return;
  const int b = idx / 5;
  const int j = idx % 5;
  float sum = b2[j];
  for (int c = 0; c < 512; ++c)
    sum += hbuf[(long)b * 512 + c] * W2[c * 5 + j];
  out[idx] = sum;
}

extern "C" void kernel_launch(void* const* d_in, const int* in_sizes, int n_in,
                              void* d_out, int out_size, void* d_ws, size_t ws_size,
                              hipStream_t stream){
  const int*   inputs = (const int*)d_in[0];
  const float* emb_tb = (const float*)d_in[1];
  const float* Wxf = (const float*)d_in[2];
  const float* Whf = (const float*)d_in[3];
  const float* bhf = (const float*)d_in[4];
  const float* Wxb = (const float*)d_in[5];
  const float* Whb = (const float*)d_in[6];
  const float* bhb = (const float*)d_in[7];
  const float* W1  = (const float*)d_in[8];
  const float* b1  = (const float*)d_in[9];
  const float* W2  = (const float*)d_in[10];
  const float* b2  = (const float*)d_in[11];
  float* out = (float*)d_out;

  char* ws = (char*)d_ws;
  size_t off = 0;
  auto alloc = [&](size_t bytes)->char*{
    char* p = ws + off; off = (off + bytes + 511) & ~(size_t)511; return p;
  };
  u32*   flags  = (u32*)alloc(1024);                           // 8 grp x 32 wg
  u16*   embA   = (u16*)alloc((size_t)32768 * 512 * 2);        // 32 MB
  u16*   WhfT   = (u16*)alloc((size_t)4096 * 1024 * 2);        //  8 MB
  u16*   WhbT   = (u16*)alloc((size_t)4096 * 1024 * 2);        //  8 MB
  u16*   WxT    = (u16*)alloc((size_t)8192 * 512 * 2);         //  8 MB
  u16*   Hbuf   = (u16*)alloc((size_t)2 * 2 * 128 * 1024 * 2); //  1 MB
  float* pooled = (float*)alloc((size_t)128 * 2048 * 4);       //  1 MB
  float* hbuf   = (float*)alloc((size_t)128 * 512 * 4);        // .25 MB

  hipMemsetAsync(flags, 0, 1024, stream);
  k_embed<<<8192, 256, 0, stream>>>(inputs, emb_tb, embA);
  k_transpose<<<dim3(128, 32), dim3(32, 8), 0, stream>>>(Whf, WhfT, 1024, 4096);
  k_transpose<<<dim3(128, 32), dim3(32, 8), 0, stream>>>(Whb, WhbT, 1024, 4096);
  k_transpose<<<dim3(128, 16), dim3(32, 8), 0, stream>>>(Wxf, WxT, 512, 4096);
  k_transpose<<<dim3(128, 16), dim3(32, 8), 0, stream>>>(Wxb, WxT + (size_t)4096 * 512, 512, 4096);
  k_recurrent<<<256, 256, 0, stream>>>(embA, WxT, WhfT, WhbT, bhf, bhb, Hbuf, pooled, flags);
  k_mlp1<<<64, 256, 0, stream>>>(pooled, W1, b1, hbuf);
  k_mlp2<<<10, 64, 0, stream>>>(hbuf, W2, b2, out);
}

// Round 3
// 3412.662 us; speedup vs baseline: 1.2409x; 1.0938x over previous
//
#include <hip/hip_runtime.h>
#include <stdint.h>

#define TSEQ 256
#define NB   128

typedef unsigned short u16;
typedef unsigned int   u32;
typedef unsigned long long u64;
typedef __attribute__((ext_vector_type(8))) short short8;  // 8 x bf16 (4 VGPRs)
typedef __attribute__((ext_vector_type(4))) float fx4;
typedef __attribute__((ext_vector_type(4))) u32  ux4;

static __device__ __forceinline__ u16 f2bf(float f){
  u32 u = __float_as_uint(f);
  u32 r = ((u >> 16) & 1u) + 0x7fffu;   // round-to-nearest-even
  return (u16)((u + r) >> 16);
}
static __device__ __forceinline__ float sigf(float x){ return 1.0f / (1.0f + __expf(-x)); }
static __device__ __forceinline__ float tanh_(float x){
  float ax = fabsf(x);
  float e  = __expf(-2.0f * ax);
  float t  = (1.0f - e) / (1.0f + e);
  return copysignf(t, x);
}

// ---------------- embedding gather + fp32->bf16 ----------------
__global__ __launch_bounds__(256) void k_embed(const int* __restrict__ tok,
                                               const float* __restrict__ tab,
                                               u16* __restrict__ embA){
  const int row  = blockIdx.x * 4 + (threadIdx.x >> 6);   // row = t*128 + b
  const int lane = threadIdx.x & 63;
  const int t = row >> 7;
  const int b = row & 127;
  const int tk = tok[b * TSEQ + t];
  const float* src = tab + (long)tk * 512 + lane * 8;
  const fx4 f0 = *(const fx4*)src;
  const fx4 f1 = *(const fx4*)(src + 4);
  ux4 w;
  w[0] = (u32)f2bf(f0[0]) | ((u32)f2bf(f0[1]) << 16);
  w[1] = (u32)f2bf(f0[2]) | ((u32)f2bf(f0[3]) << 16);
  w[2] = (u32)f2bf(f1[0]) | ((u32)f2bf(f1[1]) << 16);
  w[3] = (u32)f2bf(f1[2]) | ((u32)f2bf(f1[3]) << 16);
  *(ux4*)(embA + (long)row * 512 + lane * 8) = w;
}

// ---------------- tiled transpose fp32(RxC) -> bf16(CxR) ----------------
__global__ __launch_bounds__(256) void k_transpose(const float* __restrict__ in,
                                                   u16* __restrict__ out, int R, int C){
  __shared__ float tile[32][33];
  const int c0 = blockIdx.x * 32;
  const int r0 = blockIdx.y * 32;
  const int tx = threadIdx.x;   // 0..31
  const int ty = threadIdx.y;   // 0..7
#pragma unroll
  for (int i = 0; i < 4; ++i)
    tile[ty + i * 8][tx] = in[(long)(r0 + ty + i * 8) * C + c0 + tx];
  __syncthreads();
#pragma unroll
  for (int i = 0; i < 4; ++i)
    out[(long)(c0 + ty + i * 8) * R + r0 + tx] = f2bf(tile[tx][ty + i * 8]);
}

// ---------------- persistent bidirectional LSTM, phase-pipelined ----------------
// 8 groups = (dir x batch-quarter), 32 WGs/group (grp = bx&7 -> XCD-aligned under
// round-robin; correctness stays agent-scope = placement-independent).
// WG = 32 batches x 128 gate-cols (one gate per wave, full K=1024).
// Per-step serial chain minimized:
//   GEMM (Wh from LDS + Wx from LDS, interleaved) -> publish -> elementwise ->
//   H store -> [emb(t+1) loads issued] -> drain barrier -> flag -> emb ds_write
//   (data already landed) -> poll -> barrier -> H stage (32 loads all in flight,
//   ~1 MALL RTT) -> barrier -> next GEMM.
__global__ __launch_bounds__(256, 1) void k_recurrent(
    const u16* __restrict__ embA,                        // (T*B, 512) bf16
    const u16* __restrict__ WxT,                         // (2*4096, 512) bf16 (f then b)
    const u16* __restrict__ WhfT, const u16* __restrict__ WhbT,   // (4096,1024) bf16
    const float* __restrict__ bhf, const float* __restrict__ bhb,
    u16* __restrict__ Hbuf,                              // [2 dir][2 buf][128][1024] bf16
    float* __restrict__ pooled,                          // [128][2048] fp32 (relu'd)
    u32* __restrict__ flags)                             // [8 grp][32 wg] step counters
{
  __shared__ float P[4][32][36];      // 18.4 KB  pre-activation tiles
  __shared__ u16  Hst[32 * 1032];     // 66.0 KB  H(t-1) tile, 2064B row stride
  __shared__ u16  Est[32 * 520];      // 33.3 KB  emb(t) tile, 1040B row stride

  const int tid  = threadIdx.x;
  const int lane = tid & 63;
  const int ws   = tid >> 6;        // wave id == gate id (0..3)
  const int bx   = blockIdx.x;
  const int grp  = bx & 7;          // (dir, batch-quarter) group, XCD-aligned
  const int ch   = bx >> 3;         // 0..31 -> h block
  const int dir  = grp >> 2;
  const int bq   = grp & 3;
  const int h0   = ch * 32;
  const int b0   = bq * 32;
  const int l15  = lane & 15, l4 = lane >> 4;

  const u16*   WhT  = dir ? WhbT : WhfT;
  const float* bias = dir ? bhb : bhf;

  // persistent Wh B-frags: gate ws, cols h0..h0+31, full K=1024
  short8 Bfr[32][2];
#pragma unroll
  for (int w = 0; w < 32; ++w)
#pragma unroll
    for (int cf = 0; cf < 2; ++cf)
      Bfr[w][cf] = *(const short8*)(WhT + (long)(ws * 1024 + h0 + cf * 16 + l15) * 1024
                                        + w * 32 + l4 * 8);

  // Wx row pointers (B-operand of the x-projection GEMM; stays L2-hot, 2MB/XCD)
  const u16* rowBx[2];
#pragma unroll
  for (int cf = 0; cf < 2; ++cf)
    rowBx[cf] = WxT + ((long)dir * 4096 + ws * 1024 + h0 + cf * 16 + l15) * 512 + l4 * 8;

  const int bl = tid >> 3;               // local batch 0..31
  const int hq = tid & 7;                // h-quad within 32-col block
  const int bg = b0 + bl;

  fx4 bsv[4];
#pragma unroll
  for (int g = 0; g < 4; ++g)
    bsv[g] = *(const fx4*)(bias + g * 1024 + h0 + hq * 4);

  float Creg[4] = {0.f, 0.f, 0.f, 0.f};
  float pmax[4] = {-3.0e38f, -3.0e38f, -3.0e38f, -3.0e38f};

  // ---- emb staging helpers: issue-early (regs), write-late (LDS) ----
  ux4 ebuf[8];
  auto emb_issue = [&](int tt){
    const long er = (long)(dir ? (TSEQ - 1 - tt) : tt) * NB + b0 + ws * 8;
    const u16* src = embA + er * 512 + lane * 8;
#pragma unroll
    for (int r = 0; r < 8; ++r)
      ebuf[r] = *(const ux4*)(src + (long)r * 512);
  };
  auto emb_write = [&](){
    char* dst = (char*)Est + (ws * 8) * 1040 + lane * 16;
#pragma unroll
    for (int r = 0; r < 8; ++r)
      *(ux4*)(dst + r * 1040) = ebuf[r];
  };

  // prologue: stage emb(0)
  emb_issue(0);
  emb_write();
  __syncthreads();

  const char* ha0 = (const char*)Hst + l15 * 2064 + l4 * 16;
  const char* ha1 = ha0 + 16 * 2064;
  const char* ea0 = (const char*)Est + l15 * 1040 + l4 * 16;
  const char* ea1 = ea0 + 16 * 1040;

  for (int t = 0; t < TSEQ; ++t){
    fx4 acc[2][2];
#pragma unroll
    for (int rf = 0; rf < 2; ++rf)
#pragma unroll
      for (int cf = 0; cf < 2; ++cf)
#pragma unroll
        for (int r = 0; r < 4; ++r) acc[rf][cf][r] = 0.f;

    // ---- merged GEMM phase: Wh (K=1024, from Hst) + Wx (K=512, from Est) ----
    if (t > 0){
#pragma unroll
      for (int w = 0; w < 16; ++w){
        short8 e0  = *(const short8*)(ea0 + w * 64);
        short8 e1  = *(const short8*)(ea1 + w * 64);
        short8 bx0 = *(const short8*)(rowBx[0] + w * 32);
        short8 bx1 = *(const short8*)(rowBx[1] + w * 32);
        short8 h00 = *(const short8*)(ha0 + (2 * w) * 64);
        short8 h10 = *(const short8*)(ha1 + (2 * w) * 64);
        short8 h01 = *(const short8*)(ha0 + (2 * w + 1) * 64);
        short8 h11 = *(const short8*)(ha1 + (2 * w + 1) * 64);
        acc[0][0] = __builtin_amdgcn_mfma_f32_16x16x32_bf16(h00, Bfr[2*w][0],   acc[0][0], 0, 0, 0);
        acc[0][1] = __builtin_amdgcn_mfma_f32_16x16x32_bf16(h00, Bfr[2*w][1],   acc[0][1], 0, 0, 0);
        acc[1][0] = __builtin_amdgcn_mfma_f32_16x16x32_bf16(h10, Bfr[2*w][0],   acc[1][0], 0, 0, 0);
        acc[1][1] = __builtin_amdgcn_mfma_f32_16x16x32_bf16(h10, Bfr[2*w][1],   acc[1][1], 0, 0, 0);
        acc[0][0] = __builtin_amdgcn_mfma_f32_16x16x32_bf16(e0,  bx0,           acc[0][0], 0, 0, 0);
        acc[0][1] = __builtin_amdgcn_mfma_f32_16x16x32_bf16(e0,  bx1,           acc[0][1], 0, 0, 0);
        acc[1][0] = __builtin_amdgcn_mfma_f32_16x16x32_bf16(e1,  bx0,           acc[1][0], 0, 0, 0);
        acc[1][1] = __builtin_amdgcn_mfma_f32_16x16x32_bf16(e1,  bx1,           acc[1][1], 0, 0, 0);
        acc[0][0] = __builtin_amdgcn_mfma_f32_16x16x32_bf16(h01, Bfr[2*w+1][0], acc[0][0], 0, 0, 0);
        acc[0][1] = __builtin_amdgcn_mfma_f32_16x16x32_bf16(h01, Bfr[2*w+1][1], acc[0][1], 0, 0, 0);
        acc[1][0] = __builtin_amdgcn_mfma_f32_16x16x32_bf16(h11, Bfr[2*w+1][0], acc[1][0], 0, 0, 0);
        acc[1][1] = __builtin_amdgcn_mfma_f32_16x16x32_bf16(h11, Bfr[2*w+1][1], acc[1][1], 0, 0, 0);
      }
    } else {
#pragma unroll
      for (int w = 0; w < 16; ++w){
        short8 e0  = *(const short8*)(ea0 + w * 64);
        short8 e1  = *(const short8*)(ea1 + w * 64);
        short8 bx0 = *(const short8*)(rowBx[0] + w * 32);
        short8 bx1 = *(const short8*)(rowBx[1] + w * 32);
        acc[0][0] = __builtin_amdgcn_mfma_f32_16x16x32_bf16(e0, bx0, acc[0][0], 0, 0, 0);
        acc[0][1] = __builtin_amdgcn_mfma_f32_16x16x32_bf16(e0, bx1, acc[0][1], 0, 0, 0);
        acc[1][0] = __builtin_amdgcn_mfma_f32_16x16x32_bf16(e1, bx0, acc[1][0], 0, 0, 0);
        acc[1][1] = __builtin_amdgcn_mfma_f32_16x16x32_bf16(e1, bx1, acc[1][1], 0, 0, 0);
      }
    }

    // ---- publish this gate's 32x32 pre-activation tile ----
#pragma unroll
    for (int rf = 0; rf < 2; ++rf)
#pragma unroll
      for (int cf = 0; cf < 2; ++cf)
#pragma unroll
        for (int r = 0; r < 4; ++r)
          P[ws][rf * 16 + l4 * 4 + r][cf * 16 + l15] = acc[rf][cf][r];

    __syncthreads();

    // ---- elementwise: thread owns (1 batch x 4 h); C and max in registers ----
    float gv[4][4];
#pragma unroll
    for (int g = 0; g < 4; ++g){
      const fx4 p = *(const fx4*)&P[g][bl][hq * 4];
#pragma unroll
      for (int j = 0; j < 4; ++j) gv[g][j] = p[j] + bsv[g][j];
    }

    u16 hb16[4];
#pragma unroll
    for (int j = 0; j < 4; ++j){
      float i_, f_, o_;
      if (dir == 0){
        i_ = sigf(gv[0][j]); f_ = sigf(gv[1][j]); o_ = sigf(gv[2][j]);
      } else {  // reference applies sigmoid twice on backward i/f/o
        i_ = sigf(sigf(gv[0][j])); f_ = sigf(sigf(gv[1][j])); o_ = sigf(sigf(gv[2][j]));
      }
      const float cn = tanh_(gv[3][j]);
      Creg[j] = f_ * Creg[j] + i_ * cn;
      const float h = o_ * tanh_(Creg[j]);
      pmax[j] = fmaxf(pmax[j], h);
      hb16[j] = f2bf(h);
    }
    {  // H(t) store: agent-scope (visible at device coherence point)
      u16* hw = Hbuf + (((long)dir * 2 + (t & 1)) * 128 + bg) * 1024 + h0 + hq * 4;
      u64 pk = (u64)hb16[0] | ((u64)hb16[1] << 16) | ((u64)hb16[2] << 32) | ((u64)hb16[3] << 48);
      __hip_atomic_store((u64*)hw, pk, __ATOMIC_RELAXED, __HIP_MEMORY_SCOPE_AGENT);
    }

    if (t + 1 < TSEQ){
      emb_issue(t + 1);      // overlaps the store-drain below
      __syncthreads();       // vmcnt(0): H stores globally visible, emb data landed
      if (tid == 0)
        __hip_atomic_store(&flags[grp * 32 + ch], (u32)(t + 1),
                           __ATOMIC_RELAXED, __HIP_MEMORY_SCOPE_AGENT);
      emb_write();           // zero-stall: data already in regs

      if (ws == 0){          // one wave polls; others park at the barrier
        const u32 target = (u32)(t + 1);
        const u32* fl = flags + grp * 32;
        for (;;){
          const u32 v = __hip_atomic_load(&fl[lane & 31], __ATOMIC_RELAXED,
                                          __HIP_MEMORY_SCOPE_AGENT);
          if (__all(v >= target)) break;
        }
      }
      __asm__ volatile("" ::: "memory");
      __syncthreads();

      // ---- stage H(t): 32 agent loads ALL in flight, then LDS writes ----
      {
        const u16* gs = Hbuf + (((long)dir * 2 + (t & 1)) * 128 + b0 + ws * 8) * 1024
                      + lane * 4;
        u64 ta[16], tb[16];
#pragma unroll
        for (int c = 0; c < 16; ++c)
          ta[c] = __hip_atomic_load((const u64*)(gs + (c >> 2) * 1024 + (c & 3) * 256),
                                    __ATOMIC_RELAXED, __HIP_MEMORY_SCOPE_AGENT);
#pragma unroll
        for (int c = 0; c < 16; ++c)
          tb[c] = __hip_atomic_load((const u64*)(gs + (4 + (c >> 2)) * 1024 + (c & 3) * 256),
                                    __ATOMIC_RELAXED, __HIP_MEMORY_SCOPE_AGENT);
        char* hd = (char*)Hst + (ws * 8) * 2064 + lane * 8;
#pragma unroll
        for (int c = 0; c < 16; ++c)
          *(u64*)(hd + (c >> 2) * 2064 + (c & 3) * 512) = ta[c];
#pragma unroll
        for (int c = 0; c < 16; ++c)
          *(u64*)(hd + (4 + (c >> 2)) * 2064 + (c & 3) * 512) = tb[c];
      }
      __syncthreads();
    }
  }

  {  // relu(maxpool) in fp32 for the MLP head
    float* pw = pooled + (long)bg * 2048 + dir * 1024 + h0 + hq * 4;
    fx4 pv;
#pragma unroll
    for (int j = 0; j < 4; ++j) pv[j] = fmaxf(pmax[j], 0.f);
    *(fx4*)pw = pv;
  }
}

// ---------------- MLP layer 1 (fp32): h = relu(pooled) @ W1 + b1 ----------------
__global__ __launch_bounds__(256) void k_mlp1(const float* __restrict__ pooled,
                                              const float* __restrict__ W1,
                                              const float* __restrict__ b1,
                                              float* __restrict__ hbuf){
  const int cb = blockIdx.x & 7, bb = blockIdx.x >> 3;
  const int c  = cb * 64 + (threadIdx.x & 63);
  const int bq = threadIdx.x >> 6;
  const int b0 = bb * 16 + bq * 4;
  float a0 = 0.f, a1 = 0.f, a2 = 0.f, a3 = 0.f;
  for (int k = 0; k < 2048; k += 4){
    const fx4 p0 = *(const fx4*)(pooled + (long)(b0 + 0) * 2048 + k);
    const fx4 p1 = *(const fx4*)(pooled + (long)(b0 + 1) * 2048 + k);
    const fx4 p2 = *(const fx4*)(pooled + (long)(b0 + 2) * 2048 + k);
    const fx4 p3 = *(const fx4*)(pooled + (long)(b0 + 3) * 2048 + k);
#pragma unroll
    for (int j = 0; j < 4; ++j){
      const float w = W1[(long)(k + j) * 512 + c];
      a0 += p0[j] * w; a1 += p1[j] * w; a2 += p2[j] * w; a3 += p3[j] * w;
    }
  }
  const float bv = b1[c];
  hbuf[(long)(b0 + 0) * 512 + c] = a0 + bv;
  hbuf[(long)(b0 + 1) * 512 + c] = a1 + bv;
  hbuf[(long)(b0 + 2) * 512 + c] = a2 + bv;
  hbuf[(long)(b0 + 3) * 512 + c] = a3 + bv;
}

// ---------------- MLP layer 2 (fp32): out = h @ W2 + b2 ----------------
__global__ __launch_bounds__(64) void k_mlp2(const float* __restrict__ hbuf,
                                             const float* __restrict__ W2,
                                             const float* __restrict__ b2,
                                             float* __restrict__ out){
  const int idx = blockIdx.x * 64 + threadIdx.x;
  if (idx >= 640) return;
  const int b = idx / 5;
  const int j = idx % 5;
  float sum = b2[j];
  for (int c = 0; c < 512; ++c)
    sum += hbuf[(long)b * 512 + c] * W2[c * 5 + j];
  out[idx] = sum;
}

extern "C" void kernel_launch(void* const* d_in, const int* in_sizes, int n_in,
                              void* d_out, int out_size, void* d_ws, size_t ws_size,
                              hipStream_t stream){
  const int*   inputs = (const int*)d_in[0];
  const float* emb_tb = (const float*)d_in[1];
  const float* Wxf = (const float*)d_in[2];
  const float* Whf = (const float*)d_in[3];
  const float* bhf = (const float*)d_in[4];
  const float* Wxb = (const float*)d_in[5];
  const float* Whb = (const float*)d_in[6];
  const float* bhb = (const float*)d_in[7];
  const float* W1  = (const float*)d_in[8];
  const float* b1  = (const float*)d_in[9];
  const float* W2  = (const float*)d_in[10];
  const float* b2  = (const float*)d_in[11];
  float* out = (float*)d_out;

  char* ws = (char*)d_ws;
  size_t off = 0;
  auto alloc = [&](size_t bytes)->char*{
    char* p = ws + off; off = (off + bytes + 511) & ~(size_t)511; return p;
  };
  u32*   flags  = (u32*)alloc(1024);                           // 8 grp x 32 wg
  u16*   embA   = (u16*)alloc((size_t)32768 * 512 * 2);        // 32 MB
  u16*   WhfT   = (u16*)alloc((size_t)4096 * 1024 * 2);        //  8 MB
  u16*   WhbT   = (u16*)alloc((size_t)4096 * 1024 * 2);        //  8 MB
  u16*   WxT    = (u16*)alloc((size_t)8192 * 512 * 2);         //  8 MB
  u16*   Hbuf   = (u16*)alloc((size_t)2 * 2 * 128 * 1024 * 2); //  1 MB
  float* pooled = (float*)alloc((size_t)128 * 2048 * 4);       //  1 MB
  float* hbuf   = (float*)alloc((size_t)128 * 512 * 4);        // .25 MB

  hipMemsetAsync(flags, 0, 1024, stream);
  k_embed<<<8192, 256, 0, stream>>>(inputs, emb_tb, embA);
  k_transpose<<<dim3(128, 32), dim3(32, 8), 0, stream>>>(Whf, WhfT, 1024, 4096);
  k_transpose<<<dim3(128, 32), dim3(32, 8), 0, stream>>>(Whb, WhbT, 1024, 4096);
  k_transpose<<<dim3(128, 16), dim3(32, 8), 0, stream>>>(Wxf, WxT, 512, 4096);
  k_transpose<<<dim3(128, 16), dim3(32, 8), 0, stream>>>(Wxb, WxT + (size_t)4096 * 512, 512, 4096);
  k_recurrent<<<256, 256, 0, stream>>>(embA, WxT, WhfT, WhbT, bhf, bhb, Hbuf, pooled, flags);
  k_mlp1<<<64, 256, 0, stream>>>(pooled, W1, b1, hbuf);
  k_mlp2<<<10, 64, 0, stream>>>(hbuf, W2, b2, out);
}

// Round 7
// 2025.196 us; speedup vs baseline: 2.0910x; 1.6851x over previous
//
#include <hip/hip_runtime.h>
#include <stdint.h>

#define TSEQ 256
#define NB   128

typedef unsigned short u16;
typedef unsigned int   u32;
typedef unsigned long long u64;
typedef __attribute__((ext_vector_type(8))) short short8;  // 8 x bf16 (4 VGPRs)
typedef __attribute__((ext_vector_type(4))) float fx4;
typedef __attribute__((ext_vector_type(4))) u32  ux4;

static __device__ __forceinline__ u16 f2bf(float f){
  u32 u = __float_as_uint(f);
  u32 r = ((u >> 16) & 1u) + 0x7fffu;   // round-to-nearest-even
  return (u16)((u + r) >> 16);
}
static __device__ __forceinline__ float sigf(float x){ return 1.0f / (1.0f + __expf(-x)); }
static __device__ __forceinline__ float tanh_(float x){
  float ax = fabsf(x);
  float e  = __expf(-2.0f * ax);
  float t  = (1.0f - e) / (1.0f + e);
  return copysignf(t, x);
}

// ---------------- embedding gather + fp32->bf16 ----------------
__global__ __launch_bounds__(256) void k_embed(const int* __restrict__ tok,
                                               const float* __restrict__ tab,
                                               u16* __restrict__ embA){
  const int row  = blockIdx.x * 4 + (threadIdx.x >> 6);   // row = t*128 + b
  const int lane = threadIdx.x & 63;
  const int t = row >> 7;
  const int b = row & 127;
  const int tk = tok[b * TSEQ + t];
  const float* src = tab + (long)tk * 512 + lane * 8;
  const fx4 f0 = *(const fx4*)src;
  const fx4 f1 = *(const fx4*)(src + 4);
  ux4 w;
  w[0] = (u32)f2bf(f0[0]) | ((u32)f2bf(f0[1]) << 16);
  w[1] = (u32)f2bf(f0[2]) | ((u32)f2bf(f0[3]) << 16);
  w[2] = (u32)f2bf(f1[0]) | ((u32)f2bf(f1[1]) << 16);
  w[3] = (u32)f2bf(f1[2]) | ((u32)f2bf(f1[3]) << 16);
  *(ux4*)(embA + (long)row * 512 + lane * 8) = w;
}

// ---------------- tiled transpose fp32(RxC) -> bf16(CxR) ----------------
__global__ __launch_bounds__(256) void k_transpose(const float* __restrict__ in,
                                                   u16* __restrict__ out, int R, int C){
  __shared__ float tile[32][33];
  const int c0 = blockIdx.x * 32;
  const int r0 = blockIdx.y * 32;
  const int tx = threadIdx.x;   // 0..31
  const int ty = threadIdx.y;   // 0..7
#pragma unroll
  for (int i = 0; i < 4; ++i)
    tile[ty + i * 8][tx] = in[(long)(r0 + ty + i * 8) * C + c0 + tx];
  __syncthreads();
#pragma unroll
  for (int i = 0; i < 4; ++i)
    out[(long)(c0 + ty + i * 8) * R + r0 + tx] = f2bf(tile[tx][ty + i * 8]);
}

// ---------------- persistent bidirectional LSTM, phase-pipelined ----------------
// SAME sync/flag protocol as the round-2 PASSING kernel (agent-scope stores,
// per-group flag vector, single-wave parallel poll). Change: 8 waves (512 thr)
// per WG, wave = (gate g, col-half ch2) -> per-wave Wh slice is 16 cols x K=1024
// = Bfr[32] = 128 VGPRs, which ACTUALLY fits in registers (the 4-wave version
// needed 256 VGPRs for Bfr -> compiler re-streamed Wh from L2/MALL inside the
// serial GEMM phase every step). No K-split => publish/elementwise unchanged
// in structure; only indexing constants differ. 2 waves/SIMD (was 1).
__global__ __launch_bounds__(512, 2) void k_recurrent(
    const u16* __restrict__ embA,                        // (T*B, 512) bf16
    const u16* __restrict__ WxT,                         // (2*4096, 512) bf16 (f then b)
    const u16* __restrict__ WhfT, const u16* __restrict__ WhbT,   // (4096,1024) bf16
    const float* __restrict__ bhf, const float* __restrict__ bhb,
    u16* __restrict__ Hbuf,                              // [2 dir][2 buf][128][1024] bf16
    float* __restrict__ pooled,                          // [128][2048] fp32 (relu'd)
    u32* __restrict__ flags)                             // [8 grp][32 wg] step counters
{
  __shared__ float P[4][32][36];      // 18.4 KB  pre-activation tiles
  __shared__ u16  Hst[32 * 1032];     // 66.0 KB  H(t-1) tile, 2064B row stride
  __shared__ u16  Est[32 * 520];      // 33.3 KB  emb(t) tile, 1040B row stride

  const int tid  = threadIdx.x;
  const int lane = tid & 63;
  const int ws   = tid >> 6;        // wave id 0..7
  const int g    = ws >> 1;         // gate 0..3
  const int ch2  = ws & 1;          // col-half within gate's 32 cols
  const int bx   = blockIdx.x;
  const int grp  = bx & 7;          // (dir, batch-quarter) group
  const int ch   = bx >> 3;         // 0..31 -> h block
  const int dir  = grp >> 2;
  const int bq   = grp & 3;
  const int h0   = ch * 32;
  const int b0   = bq * 32;
  const int l15  = lane & 15, l4 = lane >> 4;

  const u16*   WhT  = dir ? WhbT : WhfT;
  const float* bias = dir ? bhb : bhf;

  // persistent Wh B-frags: gate g, cols h0+ch2*16 .. +15, full K=1024.
  // 32 x short8 = 128 VGPRs -> register-resident.
  short8 Bfr[32];
#pragma unroll
  for (int w = 0; w < 32; ++w)
    Bfr[w] = *(const short8*)(WhT + (long)(g * 1024 + h0 + ch2 * 16 + l15) * 1024
                                  + w * 32 + l4 * 8);

  // Wx row pointer (B-operand of the x-projection GEMM; streamed, L2-hot)
  const u16* rowBx = WxT + ((long)dir * 4096 + g * 1024 + h0 + ch2 * 16 + l15) * 512
                   + l4 * 8;

  const int bl = tid >> 4;               // local batch 0..31
  const int hq = tid & 15;               // col pair within 32-col block
  const int bg = b0 + bl;

  float bsv[4][2];
#pragma unroll
  for (int gg = 0; gg < 4; ++gg)
#pragma unroll
    for (int j = 0; j < 2; ++j)
      bsv[gg][j] = bias[gg * 1024 + h0 + hq * 2 + j];

  float Creg[2] = {0.f, 0.f};
  float pmax[2] = {-3.0e38f, -3.0e38f};

  // ---- emb staging helpers: issue-early (regs), write-late (LDS) ----
  ux4 ebuf[4];
  auto emb_issue = [&](int tt){
    const long er = (long)(dir ? (TSEQ - 1 - tt) : tt) * NB + b0 + ws * 4;
    const u16* src = embA + er * 512 + lane * 8;
#pragma unroll
    for (int r = 0; r < 4; ++r)
      ebuf[r] = *(const ux4*)(src + (long)r * 512);
  };
  auto emb_write = [&](){
    char* dst = (char*)Est + (ws * 4) * 1040 + lane * 16;
#pragma unroll
    for (int r = 0; r < 4; ++r)
      *(ux4*)(dst + r * 1040) = ebuf[r];
  };

  // prologue: stage emb(0)
  emb_issue(0);
  emb_write();
  __syncthreads();

  const char* ha0 = (const char*)Hst + l15 * 2064 + l4 * 16;
  const char* ha1 = ha0 + 16 * 2064;
  const char* ea0 = (const char*)Est + l15 * 1040 + l4 * 16;
  const char* ea1 = ea0 + 16 * 1040;

  for (int t = 0; t < TSEQ; ++t){
    fx4 acc[2];
#pragma unroll
    for (int rf = 0; rf < 2; ++rf)
#pragma unroll
      for (int r = 0; r < 4; ++r) acc[rf][r] = 0.f;

    // ---- merged GEMM: Wh (K=1024, Hst LDS, resident Bfr) + Wx (K=512, Est LDS) ----
    if (t > 0){
#pragma unroll
      for (int w = 0; w < 16; ++w){
        short8 e0  = *(const short8*)(ea0 + w * 64);
        short8 e1  = *(const short8*)(ea1 + w * 64);
        short8 bxf = *(const short8*)(rowBx + w * 32);
        short8 h00 = *(const short8*)(ha0 + (2 * w) * 64);
        short8 h10 = *(const short8*)(ha1 + (2 * w) * 64);
        short8 h01 = *(const short8*)(ha0 + (2 * w + 1) * 64);
        short8 h11 = *(const short8*)(ha1 + (2 * w + 1) * 64);
        acc[0] = __builtin_amdgcn_mfma_f32_16x16x32_bf16(h00, Bfr[2*w],   acc[0], 0, 0, 0);
        acc[1] = __builtin_amdgcn_mfma_f32_16x16x32_bf16(h10, Bfr[2*w],   acc[1], 0, 0, 0);
        acc[0] = __builtin_amdgcn_mfma_f32_16x16x32_bf16(e0,  bxf,        acc[0], 0, 0, 0);
        acc[1] = __builtin_amdgcn_mfma_f32_16x16x32_bf16(e1,  bxf,        acc[1], 0, 0, 0);
        acc[0] = __builtin_amdgcn_mfma_f32_16x16x32_bf16(h01, Bfr[2*w+1], acc[0], 0, 0, 0);
        acc[1] = __builtin_amdgcn_mfma_f32_16x16x32_bf16(h11, Bfr[2*w+1], acc[1], 0, 0, 0);
      }
    } else {
#pragma unroll
      for (int w = 0; w < 16; ++w){
        short8 e0  = *(const short8*)(ea0 + w * 64);
        short8 e1  = *(const short8*)(ea1 + w * 64);
        short8 bxf = *(const short8*)(rowBx + w * 32);
        acc[0] = __builtin_amdgcn_mfma_f32_16x16x32_bf16(e0, bxf, acc[0], 0, 0, 0);
        acc[1] = __builtin_amdgcn_mfma_f32_16x16x32_bf16(e1, bxf, acc[1], 0, 0, 0);
      }
    }

    // ---- publish this wave's 32x16 pre-activation tile ----
#pragma unroll
    for (int rf = 0; rf < 2; ++rf)
#pragma unroll
      for (int r = 0; r < 4; ++r)
        P[g][rf * 16 + l4 * 4 + r][ch2 * 16 + l15] = acc[rf][r];

    __syncthreads();

    // ---- elementwise: thread owns (1 batch x 2 h); C and max in registers ----
    float gv[4][2];
#pragma unroll
    for (int gg = 0; gg < 4; ++gg){
      gv[gg][0] = P[gg][bl][hq * 2 + 0] + bsv[gg][0];
      gv[gg][1] = P[gg][bl][hq * 2 + 1] + bsv[gg][1];
    }

    u16 hb16[2];
#pragma unroll
    for (int j = 0; j < 2; ++j){
      float i_, f_, o_;
      if (dir == 0){
        i_ = sigf(gv[0][j]); f_ = sigf(gv[1][j]); o_ = sigf(gv[2][j]);
      } else {  // reference applies sigmoid twice on backward i/f/o
        i_ = sigf(sigf(gv[0][j])); f_ = sigf(sigf(gv[1][j])); o_ = sigf(sigf(gv[2][j]));
      }
      const float cn = tanh_(gv[3][j]);
      Creg[j] = f_ * Creg[j] + i_ * cn;
      const float h = o_ * tanh_(Creg[j]);
      pmax[j] = fmaxf(pmax[j], h);
      hb16[j] = f2bf(h);
    }
    {  // H(t) store: agent-scope (visible at device coherence point)
      u16* hw = Hbuf + (((long)dir * 2 + (t & 1)) * 128 + bg) * 1024 + h0 + hq * 2;
      u32 pk = (u32)hb16[0] | ((u32)hb16[1] << 16);
      __hip_atomic_store((u32*)hw, pk, __ATOMIC_RELAXED, __HIP_MEMORY_SCOPE_AGENT);
    }

    if (t + 1 < TSEQ){
      emb_issue(t + 1);      // overlaps the store-drain below
      __syncthreads();       // vmcnt(0): H stores at coherence point, emb landed
      if (tid == 0)
        __hip_atomic_store(&flags[grp * 32 + ch], (u32)(t + 1),
                           __ATOMIC_RELAXED, __HIP_MEMORY_SCOPE_AGENT);
      emb_write();           // zero-stall: data already in regs

      if (ws == 0){          // one wave polls; others park at the barrier
        const u32 target = (u32)(t + 1);
        const u32* fl = flags + grp * 32;
        for (;;){
          const u32 v = __hip_atomic_load(&fl[lane & 31], __ATOMIC_RELAXED,
                                          __HIP_MEMORY_SCOPE_AGENT);
          if (__all(v >= target)) break;
        }
      }
      __asm__ volatile("" ::: "memory");
      __syncthreads();

      // ---- stage H(t): 16 agent loads ALL in flight per thread, then LDS ----
      {
        const u16* gs = Hbuf + (((long)dir * 2 + (t & 1)) * 128 + b0 + ws * 4) * 1024
                      + lane * 4;
        u64 ta[16];
#pragma unroll
        for (int c = 0; c < 16; ++c)
          ta[c] = __hip_atomic_load((const u64*)(gs + (c >> 2) * 1024 + (c & 3) * 256),
                                    __ATOMIC_RELAXED, __HIP_MEMORY_SCOPE_AGENT);
        char* hd = (char*)Hst + (ws * 4) * 2064 + lane * 8;
#pragma unroll
        for (int c = 0; c < 16; ++c)
          *(u64*)(hd + (c >> 2) * 2064 + (c & 3) * 512) = ta[c];
      }
      __syncthreads();
    }
  }

  {  // relu(maxpool) in fp32 for the MLP head
    float* pw = pooled + (long)bg * 2048 + dir * 1024 + h0 + hq * 2;
    pw[0] = fmaxf(pmax[0], 0.f);
    pw[1] = fmaxf(pmax[1], 0.f);
  }
}

// ---------------- MLP layer 1 (fp32): h = relu(pooled) @ W1 + b1 ----------------
__global__ __launch_bounds__(256) void k_mlp1(const float* __restrict__ pooled,
                                              const float* __restrict__ W1,
                                              const float* __restrict__ b1,
                                              float* __restrict__ hbuf){
  const int cb = blockIdx.x & 7, bb = blockIdx.x >> 3;
  const int c  = cb * 64 + (threadIdx.x & 63);
  const int bq = threadIdx.x >> 6;
  const int b0 = bb * 16 + bq * 4;
  float a0 = 0.f, a1 = 0.f, a2 = 0.f, a3 = 0.f;
  for (int k = 0; k < 2048; k += 4){
    const fx4 p0 = *(const fx4*)(pooled + (long)(b0 + 0) * 2048 + k);
    const fx4 p1 = *(const fx4*)(pooled + (long)(b0 + 1) * 2048 + k);
    const fx4 p2 = *(const fx4*)(pooled + (long)(b0 + 2) * 2048 + k);
    const fx4 p3 = *(const fx4*)(pooled + (long)(b0 + 3) * 2048 + k);
#pragma unroll
    for (int j = 0; j < 4; ++j){
      const float w = W1[(long)(k + j) * 512 + c];
      a0 += p0[j] * w; a1 += p1[j] * w; a2 += p2[j] * w; a3 += p3[j] * w;
    }
  }
  const float bv = b1[c];
  hbuf[(long)(b0 + 0) * 512 + c] = a0 + bv;
  hbuf[(long)(b0 + 1) * 512 + c] = a1 + bv;
  hbuf[(long)(b0 + 2) * 512 + c] = a2 + bv;
  hbuf[(long)(b0 + 3) * 512 + c] = a3 + bv;
}

// ---------------- MLP layer 2 (fp32): out = h @ W2 + b2 ----------------
__global__ __launch_bounds__(64) void k_mlp2(const float* __restrict__ hbuf,
                                             const float* __restrict__ W2,
                                             const float* __restrict__ b2,
                                             float* __restrict__ out){
  const int idx = blockIdx.x * 64 + threadIdx.x;
  if (idx >= 640) return;
  const int b = idx / 5;
  const int j = idx % 5;
  float sum = b2[j];
  for (int c = 0; c < 512; ++c)
    sum += hbuf[(long)b * 512 + c] * W2[c * 5 + j];
  out[idx] = sum;
}

extern "C" void kernel_launch(void* const* d_in, const int* in_sizes, int n_in,
                              void* d_out, int out_size, void* d_ws, size_t ws_size,
                              hipStream_t stream){
  const int*   inputs = (const int*)d_in[0];
  const float* emb_tb = (const float*)d_in[1];
  const float* Wxf = (const float*)d_in[2];
  const float* Whf = (const float*)d_in[3];
  const float* bhf = (const float*)d_in[4];
  const float* Wxb = (const float*)d_in[5];
  const float* Whb = (const float*)d_in[6];
  const float* bhb = (const float*)d_in[7];
  const float* W1  = (const float*)d_in[8];
  const float* b1  = (const float*)d_in[9];
  const float* W2  = (const float*)d_in[10];
  const float* b2  = (const float*)d_in[11];
  float* out = (float*)d_out;

  char* ws = (char*)d_ws;
  size_t off = 0;
  auto alloc = [&](size_t bytes)->char*{
    char* p = ws + off; off = (off + bytes + 511) & ~(size_t)511; return p;
  };
  u32*   flags  = (u32*)alloc(1024);                           // 8 grp x 32 wg
  u16*   embA   = (u16*)alloc((size_t)32768 * 512 * 2);        // 32 MB
  u16*   WhfT   = (u16*)alloc((size_t)4096 * 1024 * 2);        //  8 MB
  u16*   WhbT   = (u16*)alloc((size_t)4096 * 1024 * 2);        //  8 MB
  u16*   WxT    = (u16*)alloc((size_t)8192 * 512 * 2);         //  8 MB
  u16*   Hbuf   = (u16*)alloc((size_t)2 * 2 * 128 * 1024 * 2); //  1 MB
  float* pooled = (float*)alloc((size_t)128 * 2048 * 4);       //  1 MB
  float* hbuf   = (float*)alloc((size_t)128 * 512 * 4);        // .25 MB

  hipMemsetAsync(flags, 0, 1024, stream);
  k_embed<<<8192, 256, 0, stream>>>(inputs, emb_tb, embA);
  k_transpose<<<dim3(128, 32), dim3(32, 8), 0, stream>>>(Whf, WhfT, 1024, 4096);
  k_transpose<<<dim3(128, 32), dim3(32, 8), 0, stream>>>(Whb, WhbT, 1024, 4096);
  k_transpose<<<dim3(128, 16), dim3(32, 8), 0, stream>>>(Wxf, WxT, 512, 4096);
  k_transpose<<<dim3(128, 16), dim3(32, 8), 0, stream>>>(Wxb, WxT + (size_t)4096 * 512, 512, 4096);
  k_recurrent<<<256, 512, 0, stream>>>(embA, WxT, WhfT, WhbT, bhf, bhb, Hbuf, pooled, flags);
  k_mlp1<<<64, 256, 0, stream>>>(pooled, W1, b1, hbuf);
  k_mlp2<<<10, 64, 0, stream>>>(hbuf, W2, b2, out);
}